// Round 7
// baseline (369.873 us; speedup 1.0000x reference)
//
#include <hip/hip_runtime.h>
#include <hip/hip_bf16.h>

#define CIN 128
#define COUT 512
#define NEG_SLOPE 0.1f

typedef __bf16 bf16x8 __attribute__((ext_vector_type(8)));
typedef float f32x4 __attribute__((ext_vector_type(4)));

static __device__ __forceinline__ unsigned short f2bf(float f) {
  unsigned int u = __builtin_bit_cast(unsigned int, f);
  unsigned int lsb = (u >> 16) & 1u;
  u += 0x7fffu + lsb;  // round-to-nearest-even
  return (unsigned short)(u >> 16);
}
static __device__ __forceinline__ float bf_lo(unsigned int u) {
  return __builtin_bit_cast(float, u << 16);
}
static __device__ __forceinline__ float bf_hi(unsigned int u) {
  return __builtin_bit_cast(float, u & 0xffff0000u);
}
static __device__ __forceinline__ unsigned int pack2(float lo, float hi) {
  return (unsigned int)f2bf(lo) | ((unsigned int)f2bf(hi) << 16);
}

// Fused int64/int32 self-detection + decode + degree count + per-edge rank.
// int64 storage: every odd int32 word of the src half is 0 (ids < 2^31).
// Each block votes over its own 256 odd words (addresses safe in both
// encodings).
__global__ void decode_count_kernel(const int* __restrict__ raw,
                                    int* __restrict__ srcA, int* __restrict__ dstA,
                                    int* __restrict__ rank, int* __restrict__ cnt,
                                    int E, int N) {
  __shared__ int s_is32;
  if (threadIdx.x == 0) s_is32 = 0;
  __syncthreads();
  int e = blockIdx.x * blockDim.x + threadIdx.x;
  int probe = 0;
  if (e < E) probe = raw[2 * e + 1];
  if (probe != 0) s_is32 = 1;  // benign race: any writer writes 1
  __syncthreads();
  if (e >= E) return;
  int s, d;
  if (!s_is32) {  // int64: value in low word of each 8B pair
    int2 sv = ((const int2*)raw)[e];
    int2 dv = ((const int2*)raw)[E + e];
    s = sv.x;
    d = dv.x;
  } else {  // int32 packed
    s = raw[e];
    d = raw[E + e];
  }
  if ((unsigned)s >= (unsigned)N) s = 0;
  if ((unsigned)d >= (unsigned)N) d = 0;
  srcA[e] = s;
  dstA[e] = d;
  rank[e] = atomicAdd(&cnt[d], 1);
}

// Single-pass scan: block-local exclusive scan + block base from a global
// atomic cursor (CSR segments in block-arrival order -- valid partition).
__global__ __launch_bounds__(256) void scan_kernel(const int* __restrict__ cnt,
                                                   int* __restrict__ rowptr,
                                                   int* __restrict__ gcur, int N) {
  __shared__ int buf[256];
  __shared__ int sbase;
  int tid = threadIdx.x;
  int base = blockIdx.x * 1024 + tid * 4;
  int v[4];
  int tot = 0;
#pragma unroll
  for (int k = 0; k < 4; ++k) {
    int i = base + k;
    v[k] = (i < N) ? cnt[i] : 0;
    tot += v[k];
  }
  buf[tid] = tot;
  __syncthreads();
  for (int off = 1; off < 256; off <<= 1) {
    int t = (tid >= off) ? buf[tid - off] : 0;
    __syncthreads();
    buf[tid] += t;
    __syncthreads();
  }
  if (tid == 255) sbase = atomicAdd(gcur, buf[255]);  // device-scope
  __syncthreads();
  int run = sbase + buf[tid] - tot;
#pragma unroll
  for (int k = 0; k < 4; ++k) {
    int i = base + k;
    if (i < N) rowptr[i] = run;
    run += v[k];
  }
}

// Merged scatter (idx < E) + SLICED xscale (idx < N*16) + W->bf16 fragment
// shuffle (next 8192 16B-groups).
// xs layout: 4 slices of 32 channels, xs[slice][node][32] bf16 -- each slice
// is a 3.2 MB gather table that FITS per-XCD L2 (4 MB). Thread handles 8
// channels: node = idx>>4, part = idx&15, slice = part>>2, ch = (part&3)*8.
// Wshuf: fragment elem j of (wave,nt,kk,lane) at
// Wshuf[(((wave*8+nt)*4+kk)*64+lane)*8+j] (gemm wf loads = 1 KB contiguous).
__global__ __launch_bounds__(256) void scatter_prep_kernel(
    const int* __restrict__ srcA, const int* __restrict__ dstA,
    const int* __restrict__ rank, const int* __restrict__ rowptr,
    int* __restrict__ col, int E,
    const float* __restrict__ x, const int* __restrict__ cnt,
    unsigned short* __restrict__ xs,
    const float* __restrict__ W, unsigned short* __restrict__ Wbf, int N) {
  int idx = blockIdx.x * blockDim.x + threadIdx.x;
  if (idx < E) {
    int d = dstA[idx];
    col[rowptr[d] + rank[idx]] = srcA[idx];
  }
  int nx = N * 16;  // 16 8-channel groups per node
  if (idx < nx) {
    int node = idx >> 4;
    int part = idx & 15;
    int slice = part >> 2;
    float d = 1.0f / sqrtf((float)(cnt[node] + 1));  // +1 = self-loop
    const float* src = x + (size_t)node * CIN + part * 8;
    float4 v0 = *(const float4*)src;
    float4 v1 = *(const float4*)(src + 4);
    uint4 o;
    o.x = pack2(v0.x * d, v0.y * d);
    o.y = pack2(v0.z * d, v0.w * d);
    o.z = pack2(v1.x * d, v1.y * d);
    o.w = pack2(v1.z * d, v1.w * d);
    *(uint4*)&xs[((size_t)slice * N + node) * 32 + (part & 3) * 8] = o;
  } else {
    int t = idx - nx;  // one 16B fragment (8 bf16) of Wshuf
    if (t < (COUT * CIN / 8)) {
      int lane = t & 63;
      int kk = (t >> 6) & 3;
      int nt = (t >> 8) & 7;
      int wv = t >> 11;  // 0..3
      int row = wv * 128 + nt * 16 + (lane & 15);
      int c = kk * 32 + (lane >> 4) * 8;
      const float* src = W + (size_t)row * CIN + c;
      float4 v0 = *(const float4*)src;
      float4 v1 = *(const float4*)(src + 4);
      ushort4 o0, o1;
      o0.x = f2bf(v0.x); o0.y = f2bf(v0.y); o0.z = f2bf(v0.z); o0.w = f2bf(v0.w);
      o1.x = f2bf(v1.x); o1.y = f2bf(v1.y); o1.z = f2bf(v1.z); o1.w = f2bf(v1.w);
      ((ushort4*)Wbf)[2 * t] = o0;
      ((ushort4*)Wbf)[2 * t + 1] = o1;
    }
  }
}

// Channel-sliced gather hop: table = [N][32ch] bf16 (64 B/row, 3.2 MB --
// L2-resident). One node per wave: grp = lane>>2 picks the row (16 rows per
// round), sub = lane&3 picks the 16B chunk. Most nodes (deg<=16) need ONE
// round. Cross-grp reduce = 4x shfl_xor. Out: SQ ? di^2*sum : di*sum.
template <bool SQ>
__global__ __launch_bounds__(256) void hop_slice_kernel(
    const unsigned short* __restrict__ Xs,   // slice table [N][32]
    const int* __restrict__ rowptr, const int* __restrict__ cnt,
    const int* __restrict__ col, unsigned short* __restrict__ Y, int N) {
  int lane = threadIdx.x & 63;
  int wid = threadIdx.x >> 6;
  int node = blockIdx.x * 4 + wid;
  if (node >= N) return;
  int sub = lane & 3;
  int grp = lane >> 2;  // 0..15
  int beg = rowptr[node];
  int num = cnt[node];
  const uint4* X4 = (const uint4*)Xs;  // one row = 4 uint4
  float acc[8] = {0.f, 0.f, 0.f, 0.f, 0.f, 0.f, 0.f, 0.f};
  if (grp == 0) {  // self-loop term
    uint4 s = X4[(size_t)node * 4 + sub];
    acc[0] = bf_lo(s.x); acc[1] = bf_hi(s.x);
    acc[2] = bf_lo(s.y); acc[3] = bf_hi(s.y);
    acc[4] = bf_lo(s.z); acc[5] = bf_hi(s.z);
    acc[6] = bf_lo(s.w); acc[7] = bf_hi(s.w);
  }
  const int* cp = col + beg;
  for (int kb = 0; kb < num; kb += 16) {
    int k = kb + grp;
    if (k < num) {
      int j = cp[k];
      uint4 v = X4[(size_t)j * 4 + sub];
      acc[0] += bf_lo(v.x); acc[1] += bf_hi(v.x);
      acc[2] += bf_lo(v.y); acc[3] += bf_hi(v.y);
      acc[4] += bf_lo(v.z); acc[5] += bf_hi(v.z);
      acc[6] += bf_lo(v.w); acc[7] += bf_hi(v.w);
    }
  }
  // reduce across the 16 grps (lane bits 2..5)
#pragma unroll
  for (int r = 0; r < 8; ++r) acc[r] += __shfl_xor(acc[r], 4, 64);
#pragma unroll
  for (int r = 0; r < 8; ++r) acc[r] += __shfl_xor(acc[r], 8, 64);
#pragma unroll
  for (int r = 0; r < 8; ++r) acc[r] += __shfl_xor(acc[r], 16, 64);
#pragma unroll
  for (int r = 0; r < 8; ++r) acc[r] += __shfl_xor(acc[r], 32, 64);
  if (grp == 0) {
    float di = 1.0f / sqrtf((float)(num + 1));
    float sc = SQ ? di * di : di;
    uint4 o;
    o.x = pack2(acc[0] * sc, acc[1] * sc);
    o.y = pack2(acc[2] * sc, acc[3] * sc);
    o.z = pack2(acc[4] * sc, acc[5] * sc);
    o.w = pack2(acc[6] * sc, acc[7] * sc);
    ((uint4*)Y)[(size_t)node * 4 + sub] = o;
  }
}

// y = h2 @ W^T + b, LeakyReLU. Block = 32 rows x full COUT=512.
// h2 is SLICED [kk][node][32ch] -> af fragment loads are fully contiguous
// (64 lanes x 16 B = 1 KB/instr; was 256-B-strided). W pre-shuffled fragment
// order (1 KB/instr). Swapped-operand MFMA (lane&15 = m, quad*4+reg = n).
// Epilogue: LDS-staged dense stores (1 KB contiguous per wave instr).
__global__ __launch_bounds__(256) void gemm_kernel(
    const unsigned short* __restrict__ Abf, const unsigned short* __restrict__ Wbf,
    const float* __restrict__ bias, float* __restrict__ out, int M) {
  __shared__ float tile[16 * 516];  // 33 KB
  int wave = threadIdx.x >> 6;
  int lane = threadIdx.x & 63;
  int quad = lane >> 4;
  int l16 = lane & 15;
  int mbase = blockIdx.x * 32;

  int m0 = mbase + l16;
  int m1 = mbase + 16 + l16;
  bool v0 = m0 < M;
  bool v1 = m1 < M;

  bf16x8 af[2][4];
#pragma unroll
  for (int kk = 0; kk < 4; ++kk) {
    af[0][kk] = v0 ? *(const bf16x8*)(Abf + ((size_t)kk * M + m0) * 32 + quad * 8) : bf16x8{};
    af[1][kk] = v1 ? *(const bf16x8*)(Abf + ((size_t)kk * M + m1) * 32 + quad * 8) : bf16x8{};
  }

  const bf16x8* Wf = (const bf16x8*)Wbf;  // fragment-ordered
  int nbase = wave * 128;
  f32x4 acc0[8], acc1[8];
#pragma unroll
  for (int nt = 0; nt < 8; ++nt) {
    bf16x8 wf[4];
#pragma unroll
    for (int kk = 0; kk < 4; ++kk)
      wf[kk] = Wf[(((wave * 8 + nt) * 4 + kk) << 6) + lane];
    f32x4 a0 = {}, a1 = {};
#pragma unroll
    for (int kk = 0; kk < 4; ++kk) {
      a0 = __builtin_amdgcn_mfma_f32_16x16x32_bf16(wf[kk], af[0][kk], a0, 0, 0, 0);
      a1 = __builtin_amdgcn_mfma_f32_16x16x32_bf16(wf[kk], af[1][kk], a1, 0, 0, 0);
    }
    acc0[nt] = a0;
    acc1[nt] = a1;
  }

#pragma unroll
  for (int half = 0; half < 2; ++half) {
    if (half) __syncthreads();  // WAR: previous half streamed out
#pragma unroll
    for (int nt = 0; nt < 8; ++nt) {
      int n0 = nbase + nt * 16 + quad * 4;
      float4 bv = *(const float4*)(bias + n0);
      f32x4 a = half ? acc1[nt] : acc0[nt];
      float4 o;
      o.x = a[0] + bv.x; o.x = (o.x >= 0.f) ? o.x : NEG_SLOPE * o.x;
      o.y = a[1] + bv.y; o.y = (o.y >= 0.f) ? o.y : NEG_SLOPE * o.y;
      o.z = a[2] + bv.z; o.z = (o.z >= 0.f) ? o.z : NEG_SLOPE * o.z;
      o.w = a[3] + bv.w; o.w = (o.w >= 0.f) ? o.w : NEG_SLOPE * o.w;
      *(float4*)&tile[l16 * 516 + n0] = o;
    }
    __syncthreads();
#pragma unroll
    for (int it = 0; it < 8; ++it) {
      int r = it * 2 + (threadIdx.x >> 7);
      int c = (threadIdx.x & 127) * 4;
      int m = mbase + half * 16 + r;
      if (m < M) *(float4*)(out + (size_t)m * COUT + c) = *(const float4*)&tile[r * 516 + c];
    }
  }
}

static inline size_t align_up(size_t v, size_t a) { return (v + a - 1) & ~(a - 1); }

extern "C" void kernel_launch(void* const* d_in, const int* in_sizes, int n_in,
                              void* d_out, int out_size, void* d_ws, size_t ws_size,
                              hipStream_t stream) {
  const float* x = (const float*)d_in[0];
  const int* edge_raw = (const int*)d_in[1];
  const float* W = (const float*)d_in[2];
  const float* b = (const float*)d_in[3];
  float* out = (float*)d_out;

  const int N = in_sizes[0] / CIN;
  const int E = in_sizes[1] / 2;
  const int NB = (N + 1023) / 1024;  // scan blocks (49 for N=50000)

  // Workspace layout. gcur sits directly before cnt so ONE memset zeroes both.
  char* w = (char*)d_ws;
  int* gcur = (int*)w;            w += 256;
  int* cnt = (int*)w;             w += align_up((size_t)N * 4, 256);
  int* rowptr = (int*)w;          w += align_up((size_t)N * 4, 256);
  int* srcA = (int*)w;            w += align_up((size_t)E * 4, 256);
  int* dstA = (int*)w;            w += align_up((size_t)E * 4, 256);
  int* rank = (int*)w;            w += align_up((size_t)E * 4, 256);
  int* col = (int*)w;             w += align_up((size_t)E * 4, 256);
  unsigned short* h1 = (unsigned short*)w;    w += align_up((size_t)N * 32 * 2, 256);   // one slice, reused 4x
  unsigned short* h2 = (unsigned short*)w;    w += align_up((size_t)N * CIN * 2, 256);  // sliced [4][N][32]
  unsigned short* Wbf = (unsigned short*)w;   w += align_up((size_t)COUT * CIN * 2, 256);

  // xs (sliced [4][N][32]) in the tail of d_out: fully consumed by the hop
  // passes, all of which complete before gemm writes out.
  size_t outb = (size_t)out_size * sizeof(float);
  size_t rowb = (size_t)N * CIN * sizeof(unsigned short);
  unsigned short* xs = (unsigned short*)((char*)d_out + (outb - rowb));

  hipMemsetAsync(gcur, 0, 256 + (size_t)N * sizeof(int), stream);

  decode_count_kernel<<<(E + 255) / 256, 256, 0, stream>>>(edge_raw, srcA, dstA, rank, cnt, E, N);
  scan_kernel<<<NB, 256, 0, stream>>>(cnt, rowptr, gcur, N);

  int prep_elems = N * 16 + COUT * CIN / 8;
  int sp_threads = (E > prep_elems) ? E : prep_elems;
  scatter_prep_kernel<<<(sp_threads + 255) / 256, 256, 0, stream>>>(
      srcA, dstA, rank, rowptr, col, E, x, cnt, xs, W, Wbf, N);

  // Per-slice two-hop: each pass's gather table (3.2 MB) is L2-resident.
  int hop_blocks = (N + 3) / 4;
  for (int s = 0; s < 4; ++s) {
    unsigned short* xs_s = xs + (size_t)s * N * 32;
    unsigned short* h2_s = h2 + (size_t)s * N * 32;
    hop_slice_kernel<true><<<hop_blocks, 256, 0, stream>>>(xs_s, rowptr, cnt, col, h1, N);
    hop_slice_kernel<false><<<hop_blocks, 256, 0, stream>>>(h1, rowptr, cnt, col, h2_s, N);
  }

  gemm_kernel<<<(N + 31) / 32, 256, 0, stream>>>(h2, Wbf, b, out, N);
}

// Round 8
// 263.278 us; speedup vs baseline: 1.4049x; 1.4049x over previous
//
#include <hip/hip_runtime.h>
#include <hip/hip_bf16.h>

#define CIN 128
#define COUT 512
#define NEG_SLOPE 0.1f

typedef __bf16 bf16x8 __attribute__((ext_vector_type(8)));
typedef float f32x4 __attribute__((ext_vector_type(4)));

static __device__ __forceinline__ unsigned short f2bf(float f) {
  unsigned int u = __builtin_bit_cast(unsigned int, f);
  unsigned int lsb = (u >> 16) & 1u;
  u += 0x7fffu + lsb;  // round-to-nearest-even
  return (unsigned short)(u >> 16);
}
static __device__ __forceinline__ float bf_lo(unsigned int u) {
  return __builtin_bit_cast(float, u << 16);
}
static __device__ __forceinline__ float bf_hi(unsigned int u) {
  return __builtin_bit_cast(float, u & 0xffff0000u);
}
static __device__ __forceinline__ unsigned int pack2(float lo, float hi) {
  return (unsigned int)f2bf(lo) | ((unsigned int)f2bf(hi) << 16);
}

// Fused int64/int32 self-detection + decode + degree count + per-edge rank.
// int64 storage: every odd int32 word of the src half is 0 (ids < 2^31).
__global__ void decode_count_kernel(const int* __restrict__ raw,
                                    int* __restrict__ srcA, int* __restrict__ dstA,
                                    int* __restrict__ rank, int* __restrict__ cnt,
                                    int E, int N) {
  __shared__ int s_is32;
  if (threadIdx.x == 0) s_is32 = 0;
  __syncthreads();
  int e = blockIdx.x * blockDim.x + threadIdx.x;
  int probe = 0;
  if (e < E) probe = raw[2 * e + 1];
  if (probe != 0) s_is32 = 1;  // benign race: any writer writes 1
  __syncthreads();
  if (e >= E) return;
  int s, d;
  if (!s_is32) {  // int64: value in low word of each 8B pair
    int2 sv = ((const int2*)raw)[e];
    int2 dv = ((const int2*)raw)[E + e];
    s = sv.x;
    d = dv.x;
  } else {  // int32 packed
    s = raw[e];
    d = raw[E + e];
  }
  if ((unsigned)s >= (unsigned)N) s = 0;
  if ((unsigned)d >= (unsigned)N) d = 0;
  srcA[e] = s;
  dstA[e] = d;
  rank[e] = atomicAdd(&cnt[d], 1);
}

// Single-pass scan: block-local exclusive scan + block base from a global
// atomic cursor (CSR segments in block-arrival order -- valid partition).
__global__ __launch_bounds__(256) void scan_kernel(const int* __restrict__ cnt,
                                                   int* __restrict__ rowptr,
                                                   int* __restrict__ gcur, int N) {
  __shared__ int buf[256];
  __shared__ int sbase;
  int tid = threadIdx.x;
  int base = blockIdx.x * 1024 + tid * 4;
  int v[4];
  int tot = 0;
#pragma unroll
  for (int k = 0; k < 4; ++k) {
    int i = base + k;
    v[k] = (i < N) ? cnt[i] : 0;
    tot += v[k];
  }
  buf[tid] = tot;
  __syncthreads();
  for (int off = 1; off < 256; off <<= 1) {
    int t = (tid >= off) ? buf[tid - off] : 0;
    __syncthreads();
    buf[tid] += t;
    __syncthreads();
  }
  if (tid == 255) sbase = atomicAdd(gcur, buf[255]);  // device-scope
  __syncthreads();
  int run = sbase + buf[tid] - tot;
#pragma unroll
  for (int k = 0; k < 4; ++k) {
    int i = base + k;
    if (i < N) rowptr[i] = run;
    run += v[k];
  }
}

// Merged scatter (idx < E) + xscale (idx < N*32) + W->bf16 MFMA-FRAGMENT
// SHUFFLE (next 8192 16B-groups). Wshuf: fragment element j of
// (wave, nt, kk, lane) at Wshuf[(((wave*8+nt)*4+kk)*64 + lane)*8 + j] so each
// gemm wf load is 64 lanes x 16 B contiguous (1 KB/instr, zero overfetch).
__global__ __launch_bounds__(256) void scatter_prep_kernel(
    const int* __restrict__ srcA, const int* __restrict__ dstA,
    const int* __restrict__ rank, const int* __restrict__ rowptr,
    int* __restrict__ col, int E,
    const float* __restrict__ x, const int* __restrict__ cnt,
    unsigned short* __restrict__ xs,
    const float* __restrict__ W, unsigned short* __restrict__ Wbf, int N) {
  int idx = blockIdx.x * blockDim.x + threadIdx.x;
  if (idx < E) {
    int d = dstA[idx];
    col[rowptr[d] + rank[idx]] = srcA[idx];
  }
  int nx = N * (CIN / 4);
  if (idx < nx) {
    int row = idx >> 5;  // 32 float4 groups per row
    float d = 1.0f / sqrtf((float)(cnt[row] + 1));  // +1 = self-loop
    float4 v = ((const float4*)x)[idx];
    ushort4 o;
    o.x = f2bf(v.x * d); o.y = f2bf(v.y * d); o.z = f2bf(v.z * d); o.w = f2bf(v.w * d);
    ((ushort4*)xs)[idx] = o;
  } else {
    int t = idx - nx;  // one 16B fragment (8 bf16) of Wshuf
    if (t < (COUT * CIN / 8)) {
      int lane = t & 63;
      int kk = (t >> 6) & 3;
      int nt = (t >> 8) & 7;
      int wv = t >> 11;  // 0..3
      int row = wv * 128 + nt * 16 + (lane & 15);
      int c = kk * 32 + (lane >> 4) * 8;
      const float* src = W + (size_t)row * CIN + c;
      float4 v0 = *(const float4*)src;
      float4 v1 = *(const float4*)(src + 4);
      ushort4 o0, o1;
      o0.x = f2bf(v0.x); o0.y = f2bf(v0.y); o0.z = f2bf(v0.z); o0.w = f2bf(v0.w);
      o1.x = f2bf(v1.x); o1.y = f2bf(v1.y); o1.z = f2bf(v1.z); o1.w = f2bf(v1.w);
      ((ushort4*)Wbf)[2 * t] = o0;
      ((ushort4*)Wbf)[2 * t + 1] = o1;
    }
  }
}

// Gather hop over pre-scaled bf16 rows (256 B/row). One node per wave; grp
// (lane>>4) picks the row, sub (lane&15) the 16B chunk -> wave-uniform trip
// count, 4 row-loads in flight per lane in the main loop.
// TAIL = ONE MASKED 4-DEEP ROUND: out-of-range k clamps to num-1 (duplicate
// loads hit the same lines; ~1 extra row/node, L2-served) and contributions
// are zeroed by selects. Median node (deg<16, ~50% under Poisson(16)) now
// runs ONE 4-deep gather round instead of 2-3 serialized 2/1/1-deep rounds.
template <bool SQ>
__global__ __launch_bounds__(256) void hop_kernel(
    const unsigned short* __restrict__ Xs,
    const int* __restrict__ rowptr, const int* __restrict__ cnt,
    const int* __restrict__ col, unsigned short* __restrict__ Y, int N) {
  int lane = threadIdx.x & 63;
  int wid = threadIdx.x >> 6;
  int node = blockIdx.x * 4 + wid;
  if (node >= N) return;
  int sub = lane & 15;
  int grp = lane >> 4;
  int beg = rowptr[node];
  int num = cnt[node];
  const uint4* X4 = (const uint4*)Xs;  // one row = 16 uint4
  float acc[8] = {0.f, 0.f, 0.f, 0.f, 0.f, 0.f, 0.f, 0.f};
  if (grp == 0) {  // self-loop term
    uint4 s = X4[(size_t)node * 16 + sub];
    acc[0] = bf_lo(s.x); acc[1] = bf_hi(s.x);
    acc[2] = bf_lo(s.y); acc[3] = bf_hi(s.y);
    acc[4] = bf_lo(s.z); acc[5] = bf_hi(s.z);
    acc[6] = bf_lo(s.w); acc[7] = bf_hi(s.w);
  }
  const int* cp = col + beg;
  int kb = 0;
  for (; kb + 16 <= num; kb += 16) {
    int j0 = cp[kb + grp];
    int j1 = cp[kb + 4 + grp];
    int j2 = cp[kb + 8 + grp];
    int j3 = cp[kb + 12 + grp];
    uint4 v0 = X4[(size_t)j0 * 16 + sub];
    uint4 v1 = X4[(size_t)j1 * 16 + sub];
    uint4 v2 = X4[(size_t)j2 * 16 + sub];
    uint4 v3 = X4[(size_t)j3 * 16 + sub];
    acc[0] += bf_lo(v0.x); acc[1] += bf_hi(v0.x);
    acc[2] += bf_lo(v0.y); acc[3] += bf_hi(v0.y);
    acc[4] += bf_lo(v0.z); acc[5] += bf_hi(v0.z);
    acc[6] += bf_lo(v0.w); acc[7] += bf_hi(v0.w);
    acc[0] += bf_lo(v1.x); acc[1] += bf_hi(v1.x);
    acc[2] += bf_lo(v1.y); acc[3] += bf_hi(v1.y);
    acc[4] += bf_lo(v1.z); acc[5] += bf_hi(v1.z);
    acc[6] += bf_lo(v1.w); acc[7] += bf_hi(v1.w);
    acc[0] += bf_lo(v2.x); acc[1] += bf_hi(v2.x);
    acc[2] += bf_lo(v2.y); acc[3] += bf_hi(v2.y);
    acc[4] += bf_lo(v2.z); acc[5] += bf_hi(v2.z);
    acc[6] += bf_lo(v2.w); acc[7] += bf_hi(v2.w);
    acc[0] += bf_lo(v3.x); acc[1] += bf_hi(v3.x);
    acc[2] += bf_lo(v3.y); acc[3] += bf_hi(v3.y);
    acc[4] += bf_lo(v3.z); acc[5] += bf_hi(v3.z);
    acc[6] += bf_lo(v3.w); acc[7] += bf_hi(v3.w);
  }
  if (kb < num) {  // masked 4-deep tail (single round)
    int last = num - 1;
    int k0 = kb + grp;
    int k1 = kb + 4 + grp;
    int k2 = kb + 8 + grp;
    int k3 = kb + 12 + grp;
    int j0 = cp[k0 < last ? k0 : last];
    int j1 = cp[k1 < last ? k1 : last];
    int j2 = cp[k2 < last ? k2 : last];
    int j3 = cp[k3 < last ? k3 : last];
    uint4 v0 = X4[(size_t)j0 * 16 + sub];
    uint4 v1 = X4[(size_t)j1 * 16 + sub];
    uint4 v2 = X4[(size_t)j2 * 16 + sub];
    uint4 v3 = X4[(size_t)j3 * 16 + sub];
    float m0 = (k0 < num) ? 1.0f : 0.0f;
    float m1 = (k1 < num) ? 1.0f : 0.0f;
    float m2 = (k2 < num) ? 1.0f : 0.0f;
    float m3 = (k3 < num) ? 1.0f : 0.0f;
    acc[0] += m0 * bf_lo(v0.x); acc[1] += m0 * bf_hi(v0.x);
    acc[2] += m0 * bf_lo(v0.y); acc[3] += m0 * bf_hi(v0.y);
    acc[4] += m0 * bf_lo(v0.z); acc[5] += m0 * bf_hi(v0.z);
    acc[6] += m0 * bf_lo(v0.w); acc[7] += m0 * bf_hi(v0.w);
    acc[0] += m1 * bf_lo(v1.x); acc[1] += m1 * bf_hi(v1.x);
    acc[2] += m1 * bf_lo(v1.y); acc[3] += m1 * bf_hi(v1.y);
    acc[4] += m1 * bf_lo(v1.z); acc[5] += m1 * bf_hi(v1.z);
    acc[6] += m1 * bf_lo(v1.w); acc[7] += m1 * bf_hi(v1.w);
    acc[0] += m2 * bf_lo(v2.x); acc[1] += m2 * bf_hi(v2.x);
    acc[2] += m2 * bf_lo(v2.y); acc[3] += m2 * bf_hi(v2.y);
    acc[4] += m2 * bf_lo(v2.z); acc[5] += m2 * bf_hi(v2.z);
    acc[6] += m2 * bf_lo(v2.w); acc[7] += m2 * bf_hi(v2.w);
    acc[0] += m3 * bf_lo(v3.x); acc[1] += m3 * bf_hi(v3.x);
    acc[2] += m3 * bf_lo(v3.y); acc[3] += m3 * bf_hi(v3.y);
    acc[4] += m3 * bf_lo(v3.z); acc[5] += m3 * bf_hi(v3.z);
    acc[6] += m3 * bf_lo(v3.w); acc[7] += m3 * bf_hi(v3.w);
  }
  // reduce across the 4 grps (lane bits 4,5)
#pragma unroll
  for (int r = 0; r < 8; ++r) acc[r] += __shfl_xor(acc[r], 16, 64);
#pragma unroll
  for (int r = 0; r < 8; ++r) acc[r] += __shfl_xor(acc[r], 32, 64);
  if (grp == 0) {
    float di = 1.0f / sqrtf((float)(num + 1));
    float sc = SQ ? di * di : di;
    uint4 o;
    o.x = pack2(acc[0] * sc, acc[1] * sc);
    o.y = pack2(acc[2] * sc, acc[3] * sc);
    o.z = pack2(acc[4] * sc, acc[5] * sc);
    o.w = pack2(acc[6] * sc, acc[7] * sc);
    ((uint4*)Y)[(size_t)node * 16 + sub] = o;
  }
}

// y = h2 @ W^T + b, LeakyReLU. Block = 32 rows x full COUT=512.
// Swapped-operand MFMA (lane&15 = m, quad*4+reg = n). W pre-shuffled into
// fragment order so every wf load is one 1 KB contiguous wave load.
// Epilogue stages each 16-row half in LDS, then dense 1 KB/instr stores.
__global__ __launch_bounds__(256) void gemm_kernel(
    const unsigned short* __restrict__ Abf, const unsigned short* __restrict__ Wbf,
    const float* __restrict__ bias, float* __restrict__ out, int M) {
  __shared__ float tile[16 * 516];  // 33 KB
  int wave = threadIdx.x >> 6;
  int lane = threadIdx.x & 63;
  int quad = lane >> 4;
  int l16 = lane & 15;
  int mbase = blockIdx.x * 32;

  int m0 = mbase + l16;
  int m1 = mbase + 16 + l16;
  bool v0 = m0 < M;
  bool v1 = m1 < M;

  bf16x8 af[2][4];
#pragma unroll
  for (int kk = 0; kk < 4; ++kk) {
    af[0][kk] = v0 ? *(const bf16x8*)(Abf + (size_t)m0 * CIN + kk * 32 + quad * 8) : bf16x8{};
    af[1][kk] = v1 ? *(const bf16x8*)(Abf + (size_t)m1 * CIN + kk * 32 + quad * 8) : bf16x8{};
  }

  const bf16x8* Wf = (const bf16x8*)Wbf;  // fragment-ordered
  int nbase = wave * 128;
  f32x4 acc0[8], acc1[8];
#pragma unroll
  for (int nt = 0; nt < 8; ++nt) {
    bf16x8 wf[4];
#pragma unroll
    for (int kk = 0; kk < 4; ++kk)
      wf[kk] = Wf[(((wave * 8 + nt) * 4 + kk) << 6) + lane];
    f32x4 a0 = {}, a1 = {};
#pragma unroll
    for (int kk = 0; kk < 4; ++kk) {
      a0 = __builtin_amdgcn_mfma_f32_16x16x32_bf16(wf[kk], af[0][kk], a0, 0, 0, 0);
      a1 = __builtin_amdgcn_mfma_f32_16x16x32_bf16(wf[kk], af[1][kk], a1, 0, 0, 0);
    }
    acc0[nt] = a0;
    acc1[nt] = a1;
  }

#pragma unroll
  for (int half = 0; half < 2; ++half) {
    if (half) __syncthreads();  // WAR: previous half streamed out
#pragma unroll
    for (int nt = 0; nt < 8; ++nt) {
      int n0 = nbase + nt * 16 + quad * 4;
      float4 bv = *(const float4*)(bias + n0);
      f32x4 a = half ? acc1[nt] : acc0[nt];
      float4 o;
      o.x = a[0] + bv.x; o.x = (o.x >= 0.f) ? o.x : NEG_SLOPE * o.x;
      o.y = a[1] + bv.y; o.y = (o.y >= 0.f) ? o.y : NEG_SLOPE * o.y;
      o.z = a[2] + bv.z; o.z = (o.z >= 0.f) ? o.z : NEG_SLOPE * o.z;
      o.w = a[3] + bv.w; o.w = (o.w >= 0.f) ? o.w : NEG_SLOPE * o.w;
      *(float4*)&tile[l16 * 516 + n0] = o;
    }
    __syncthreads();
#pragma unroll
    for (int it = 0; it < 8; ++it) {
      int r = it * 2 + (threadIdx.x >> 7);
      int c = (threadIdx.x & 127) * 4;
      int m = mbase + half * 16 + r;
      if (m < M) *(float4*)(out + (size_t)m * COUT + c) = *(const float4*)&tile[r * 516 + c];
    }
  }
}

static inline size_t align_up(size_t v, size_t a) { return (v + a - 1) & ~(a - 1); }

extern "C" void kernel_launch(void* const* d_in, const int* in_sizes, int n_in,
                              void* d_out, int out_size, void* d_ws, size_t ws_size,
                              hipStream_t stream) {
  const float* x = (const float*)d_in[0];
  const int* edge_raw = (const int*)d_in[1];
  const float* W = (const float*)d_in[2];
  const float* b = (const float*)d_in[3];
  float* out = (float*)d_out;

  const int N = in_sizes[0] / CIN;
  const int E = in_sizes[1] / 2;
  const int NB = (N + 1023) / 1024;  // scan blocks (49 for N=50000)

  // Workspace layout. gcur sits directly before cnt so ONE memset zeroes both.
  char* w = (char*)d_ws;
  int* gcur = (int*)w;            w += 256;
  int* cnt = (int*)w;             w += align_up((size_t)N * 4, 256);
  int* rowptr = (int*)w;          w += align_up((size_t)N * 4, 256);
  int* srcA = (int*)w;            w += align_up((size_t)E * 4, 256);
  int* dstA = (int*)w;            w += align_up((size_t)E * 4, 256);
  int* rank = (int*)w;            w += align_up((size_t)E * 4, 256);
  int* col = (int*)w;             w += align_up((size_t)E * 4, 256);
  unsigned short* h2bf = (unsigned short*)w;  w += align_up((size_t)N * CIN * 2, 256);
  unsigned short* Wbf = (unsigned short*)w;   w += align_up((size_t)COUT * CIN * 2, 256);

  // bf16 row buffers in the tail of d_out (scratch until GEMM's final write).
  size_t outb = (size_t)out_size * sizeof(float);
  size_t rowb = (size_t)N * CIN * sizeof(unsigned short);
  unsigned short* h1s = (unsigned short*)((char*)d_out + (outb - rowb));
  unsigned short* xs = (unsigned short*)((char*)d_out + (outb - 2 * rowb));

  hipMemsetAsync(gcur, 0, 256 + (size_t)N * sizeof(int), stream);

  decode_count_kernel<<<(E + 255) / 256, 256, 0, stream>>>(edge_raw, srcA, dstA, rank, cnt, E, N);
  scan_kernel<<<NB, 256, 0, stream>>>(cnt, rowptr, gcur, N);

  int prep_elems = N * (CIN / 4) + COUT * CIN / 8;
  int sp_threads = (E > prep_elems) ? E : prep_elems;
  scatter_prep_kernel<<<(sp_threads + 255) / 256, 256, 0, stream>>>(
      srcA, dstA, rank, rowptr, col, E, x, cnt, xs, W, Wbf, N);

  hop_kernel<true><<<(N + 3) / 4, 256, 0, stream>>>(xs, rowptr, cnt, col, h1s, N);
  hop_kernel<false><<<(N + 3) / 4, 256, 0, stream>>>(h1s, rowptr, cnt, col, h2bf, N);

  gemm_kernel<<<(N + 31) / 32, 256, 0, stream>>>(h2bf, Wbf, b, out, N);
}